// Round 14
// baseline (359.565 us; speedup 1.0000x reference)
//
#include <hip/hip_runtime.h>

typedef short bf16x8 __attribute__((ext_vector_type(8)));
typedef float f32x4 __attribute__((ext_vector_type(4)));

#define NROWS 131072L
#define DIN 1024
#define DEMB 512
#define NEXT 768   // extended B rows: 512 emb + 34 folded-head + zero tail (BN=256 x 3)

__device__ __forceinline__ unsigned short f2bf(float f) {
  unsigned u = __float_as_uint(f);
  u += 0x7FFFu + ((u >> 16) & 1u);
  return (unsigned short)(u >> 16);
}

// Pack two f32 -> two bf16 (round-half-up): 2 adds + 1 v_perm_b32 (R5+-proven).
__device__ __forceinline__ unsigned pkhi(float a, float b) {
  unsigned ua = __float_as_uint(a) + 0x8000u;
  unsigned ub = __float_as_uint(b) + 0x8000u;
  return __builtin_amdgcn_perm(ub, ua, 0x07060302u);
}

__device__ __forceinline__ float softplusf(float v) {
  return fmaxf(v, 0.f) + log1pf(expf(-fabsf(v)));
}

// ---------- kernel 0: Wb (1024x512 f32) -> WbT rows 0..511 (bf16, k-contig) ----------
__global__ __launch_bounds__(256) void wb_transpose(const float* __restrict__ Wb,
                                                    unsigned short* __restrict__ WbT) {
  int g = blockIdx.x * 256 + threadIdx.x;
  int n = g & 511;
  int kb = g >> 9;
  unsigned short tmp[8];
#pragma unroll
  for (int j = 0; j < 8; ++j)
    tmp[j] = f2bf(Wb[(kb * 8 + j) * DEMB + n]);
  uint4 v;
  v.x = (unsigned)tmp[0] | ((unsigned)tmp[1] << 16);
  v.y = (unsigned)tmp[2] | ((unsigned)tmp[3] << 16);
  v.z = (unsigned)tmp[4] | ((unsigned)tmp[5] << 16);
  v.w = (unsigned)tmp[6] | ((unsigned)tmp[7] << 16);
  *(uint4*)(WbT + (long)n * DIN + kb * 8) = v;
}

// ---------- kernel 0b: zero rows 546..767 of WbT_ext (222 rows = 113664 u32) ----------
__global__ void zero_tail(unsigned* __restrict__ p) {
  p[blockIdx.x * 256 + threadIdx.x] = 0u;
}

// ---------- kernel 0c: WbT rows 512..545 = (Wb @ W34)^T ----------
__global__ __launch_bounds__(256) void wfold_rows(const float* __restrict__ Wb,
                                                  const float* __restrict__ Wp,
                                                  const float* __restrict__ Ws,
                                                  unsigned short* __restrict__ WbT) {
  int w = threadIdx.x >> 6, lane = threadIdx.x & 63;
  int k = blockIdx.x * 4 + w;
  if (lane >= 34) return;
  const float* src;
  if (lane < 2) src = Wp + lane;
  else { int s = (lane - 2) >> 1; src = Ws + s * 1024 + (lane & 1); }
  const float* wrow = Wb + (long)k * DEMB;
  float acc = 0.f;
#pragma unroll 8
  for (int d = 0; d < DEMB; ++d) acc = fmaf(wrow[d], src[2 * d], acc);
  WbT[(long)(512 + lane) * DIN + k] = f2bf(acc);
}

// ---------- kernel 0d: bfold[j] = bb @ W34[:,j] + bias34[j] ----------
__global__ void bfold_k(const float* __restrict__ bb, const float* __restrict__ Wp,
                        const float* __restrict__ bp, const float* __restrict__ Ws,
                        const float* __restrict__ bs, float* __restrict__ bf) {
  int j = threadIdx.x;
  if (j >= 34) return;
  const float* src; float bias;
  if (j < 2) { src = Wp + j; bias = bp[j]; }
  else { int s = (j - 2) >> 1; src = Ws + s * 1024 + (j & 1); bias = bs[s * 2 + (j & 1)]; }
  float acc = bias;
  for (int d = 0; d < DEMB; ++d) acc = fmaf(bb[d], src[2 * d], acc);
  bf[j] = acc;
}

#define SB __builtin_amdgcn_sched_barrier(0)

// ---------- kernel 1: fused GEMM — 256x256 tile, 8 waves 2m x 4n (wave 128x64) ----------
// m201-geometry port: 4 phases/K-tile, each {ds_read subtile + stage issues} ->
// barrier -> lgkmcnt(0) -> setprio(1)+16 MFMA+setprio(0) -> barrier. A-frag
// row-block cached in regs across ni-half phases. A: reg->pkhi->ds_write;
// B: gload_lds pre-swizzled. vmcnt(2) before writeA; vmcnt(0) only at tile end.
__global__ __launch_bounds__(512, 1) void gemm_fused(
    const float* __restrict__ x, const unsigned short* __restrict__ wbt,
    const float* __restrict__ bb, const int* __restrict__ sid,
    const float* __restrict__ bfold, float* __restrict__ out) {
  __shared__ __align__(16) char SM[131072];   // As0|As1|Bs0|Bs1, 32 KB each
  char* const As0 = SM;
  char* const As1 = SM + 32768;
  char* const Bs0 = SM + 65536;
  char* const Bs1 = SM + 98304;

  const int t = threadIdx.x;                 // 0..511
  const int lane = t & 63;
  const int wid = t >> 6;                    // 0..7
  const int wm = wid >> 2, wn = wid & 3;     // 2m x 4n

  // XCD swizzle: 1536 blocks (%8==0); 3 consecutive swz share one mtile/XCD.
  const int bid = blockIdx.x;
  const int swz = (bid & 7) * 192 + (bid >> 3);
  const int mtile = swz / 3;
  const int ntile = swz - mtile * 3;         // 0,1 emb; 2 = head(+waste)
  const long m0 = (long)mtile * 256;
  const int n0 = ntile * 256;

  // ---- A staging: row = t>>4 (+p*32, p 0..7), f32-float4 col c = t&15 ----
  const int arow = t >> 4;
  const int abyte = arow * 128 + (((t & 15) * 8) ^ ((arow & 7) << 4));   // +p*4096
  const float* xbase = x + (m0 + arow) * DIN + (t & 15) * 4;

  // ---- B staging (gload_lds linear dest, pre-swizzled src) ----
  // chunk i 0..3: dest byte = i*8192 + t*16 -> row = i*64 + (t>>3), phys g = t&7
  const int bsg = (t & 7) ^ ((t >> 3) & 7);
  const unsigned short* bsrc = wbt + (long)(n0 + (t >> 3)) * DIN + bsg * 8;

  // ---- fragment reads: phys granule = (ks*4+lg) ^ (l15&7), 128B rows ----
  const int l15 = lane & 15, lg = lane >> 4;
  const int kg0 = ((lg ^ (l15 & 7)) << 4);           // ks=1 -> ^64
  const int aBase = (wm * 128 + l15) * 128;          // + mi*2048
  const int bBase = (wn * 64 + l15) * 128;           // + ni*2048

  f32x4 acc[8][4] = {};
  bf16x8 afc[8];
  float4 areg[8];

  auto loadA4 = [&](int pbase, int k0) {
#pragma unroll
    for (int p = 0; p < 4; ++p)
      areg[pbase + p] = *(const float4*)(xbase + (long)(pbase + p) * 32 * DIN + k0);
  };
  auto gloadB2 = [&](char* Bw, int ibase, int k0) {
#pragma unroll
    for (int i = 0; i < 2; ++i) {
      const unsigned short* gp = bsrc + (long)(ibase + i) * 64 * DIN + k0;
      __builtin_amdgcn_global_load_lds(
          (const __attribute__((address_space(1))) void*)gp,
          (__attribute__((address_space(3))) void*)(Bw + (ibase + i) * 8192 + t * 16),
          16, 0, 0);
    }
  };
  auto writeA = [&](char* Aw) {              // 8 x ds_write_b64 (16 pkhi)
#pragma unroll
    for (int p = 0; p < 8; ++p) {
      uint2 v;
      v.x = pkhi(areg[p].x, areg[p].y);
      v.y = pkhi(areg[p].z, areg[p].w);
      *(uint2*)(Aw + abyte + p * 4096) = v;
    }
  };
  auto readA8 = [&](const char* Ac, int ks) {
    const int ko = kg0 ^ (ks << 6);
#pragma unroll
    for (int mi = 0; mi < 8; ++mi)
      afc[mi] = *(const bf16x8*)(Ac + aBase + mi * 2048 + ko);
  };
  auto mfma16 = [&](bf16x8 b0, bf16x8 b1, int ni) {
    __builtin_amdgcn_s_setprio(1);
#pragma unroll
    for (int mi = 0; mi < 8; ++mi)
      acc[mi][ni] = __builtin_amdgcn_mfma_f32_16x16x32_bf16(afc[mi], b0, acc[mi][ni], 0, 0, 0);
#pragma unroll
    for (int mi = 0; mi < 8; ++mi)
      acc[mi][ni + 1] = __builtin_amdgcn_mfma_f32_16x16x32_bf16(afc[mi], b1, acc[mi][ni + 1], 0, 0, 0);
    __builtin_amdgcn_s_setprio(0);
  };
  auto bread = [&](const char* Bc, int ni, int ks) {
    return *(const bf16x8*)(Bc + bBase + ni * 2048 + (kg0 ^ (ks << 6)));
  };

  // TILE with staging of tile kS into (Aw = A-slot^1 via regs, Bw)
  auto tileS = [&](const char* Ac, const char* Bc, char* Aw, char* Bw, int kS) {
    bf16x8 b0, b1;
    // ph0: afc@ks0 + b(0,1)@ks0 ; stage A0-3, B0-1
    readA8(Ac, 0); b0 = bread(Bc, 0, 0); b1 = bread(Bc, 1, 0);
    loadA4(0, kS); gloadB2(Bw, 0, kS);
    __builtin_amdgcn_s_barrier();
    SB; asm volatile("s_waitcnt lgkmcnt(0)" ::: "memory"); SB;
    mfma16(b0, b1, 0);
    __builtin_amdgcn_s_barrier();
    // ph1: b(2,3)@ks0 ; stage A4-7, B2-3
    b0 = bread(Bc, 2, 0); b1 = bread(Bc, 3, 0);
    loadA4(4, kS); gloadB2(Bw, 2, kS);
    __builtin_amdgcn_s_barrier();
    SB; asm volatile("s_waitcnt lgkmcnt(0)" ::: "memory"); SB;
    mfma16(b0, b1, 2);
    __builtin_amdgcn_s_barrier();
    // ph2: afc@ks1 + b(0,1)@ks1
    readA8(Ac, 1); b0 = bread(Bc, 0, 1); b1 = bread(Bc, 1, 1);
    __builtin_amdgcn_s_barrier();
    SB; asm volatile("s_waitcnt lgkmcnt(0)" ::: "memory"); SB;
    mfma16(b0, b1, 0);
    __builtin_amdgcn_s_barrier();
    // ph3: b(2,3)@ks1 ; vmcnt(2) -> A regs landed -> writeA
    b0 = bread(Bc, 2, 1); b1 = bread(Bc, 3, 1);
    SB; asm volatile("s_waitcnt vmcnt(2)" ::: "memory"); SB;
    writeA(Aw);
    __builtin_amdgcn_s_barrier();
    SB; asm volatile("s_waitcnt lgkmcnt(0)" ::: "memory"); SB;
    mfma16(b0, b1, 2);
    SB; asm volatile("s_waitcnt vmcnt(0) lgkmcnt(0)" ::: "memory"); SB;
    __builtin_amdgcn_s_barrier();
  };
  auto tileN = [&](const char* Ac, const char* Bc) {   // no staging (last tile)
    bf16x8 b0, b1;
    readA8(Ac, 0); b0 = bread(Bc, 0, 0); b1 = bread(Bc, 1, 0);
    __builtin_amdgcn_s_barrier();
    SB; asm volatile("s_waitcnt lgkmcnt(0)" ::: "memory"); SB;
    mfma16(b0, b1, 0);
    __builtin_amdgcn_s_barrier();
    b0 = bread(Bc, 2, 0); b1 = bread(Bc, 3, 0);
    __builtin_amdgcn_s_barrier();
    SB; asm volatile("s_waitcnt lgkmcnt(0)" ::: "memory"); SB;
    mfma16(b0, b1, 2);
    __builtin_amdgcn_s_barrier();
    readA8(Ac, 1); b0 = bread(Bc, 0, 1); b1 = bread(Bc, 1, 1);
    __builtin_amdgcn_s_barrier();
    SB; asm volatile("s_waitcnt lgkmcnt(0)" ::: "memory"); SB;
    mfma16(b0, b1, 0);
    __builtin_amdgcn_s_barrier();
    b0 = bread(Bc, 2, 1); b1 = bread(Bc, 3, 1);
    __builtin_amdgcn_s_barrier();
    SB; asm volatile("s_waitcnt lgkmcnt(0)" ::: "memory"); SB;
    mfma16(b0, b1, 2);
  };

  // ---- prologue: tile 0 fully staged ----
  loadA4(0, 0); loadA4(4, 0);
  gloadB2(Bs0, 0, 0); gloadB2(Bs0, 2, 0);
  SB; asm volatile("s_waitcnt vmcnt(4)" ::: "memory"); SB;   // A regs landed
  writeA(As0);
  SB; asm volatile("s_waitcnt vmcnt(0) lgkmcnt(0)" ::: "memory"); SB;
  __builtin_amdgcn_s_barrier();

  // ---- tiles 0..13 (stage t+1), 14 (stage 15), 15 (none) ----
#pragma unroll 1
  for (int tb = 0; tb < 14; tb += 2) {
    tileS(As0, Bs0, As1, Bs1, (tb + 1) * 64);
    tileS(As1, Bs1, As0, Bs0, (tb + 2) * 64);
  }
  tileS(As0, Bs0, As1, Bs1, 15 * 64);
  tileN(As1, Bs1);

  // ---- epilogue ----
  if (ntile < 2) {
    const int colg = n0 + wn * 64 + l15;
    float bbv[4];
#pragma unroll
    for (int ni = 0; ni < 4; ++ni) bbv[ni] = bb[colg + ni * 16];
#pragma unroll
    for (int mi = 0; mi < 8; ++mi) {
      const long rbase = m0 + wm * 128 + mi * 16 + lg * 4;
#pragma unroll
      for (int ni = 0; ni < 4; ++ni)
#pragma unroll
        for (int r = 0; r < 4; ++r)
          out[(rbase + r) * DEMB + colg + ni * 16] = acc[mi][ni][r] + bbv[ni];
    }
  } else {
    // head tile: acc cols 0..33 (global 512..545) -> gather selected per row
    __syncthreads();
    float* hl = (float*)SM;                  // [256][35] f32 = 35 KB overlay
    if (wn == 0) {
#pragma unroll
      for (int ni = 0; ni < 3; ++ni) {
#pragma unroll
        for (int mi = 0; mi < 8; ++mi)
#pragma unroll
          for (int r = 0; r < 4; ++r) {
            int row = wm * 128 + mi * 16 + lg * 4 + r;
            int col = ni * 16 + l15;
            if (col < 35) hl[row * 35 + col] = acc[mi][ni][r];
          }
      }
    }
    __syncthreads();
    if (t < 256) {
      const long row = m0 + t;
      const int s = sid[row];
      const float v0 = hl[t * 35 + 0] + bfold[0];
      const float v1 = hl[t * 35 + 1] + bfold[1];
      const float v2 = hl[t * 35 + 2 + 2 * s] + bfold[2 + 2 * s];
      const float v3 = hl[t * 35 + 3 + 2 * s] + bfold[3 + 2 * s];
      float* hp = out + NROWS * DEMB;
      hp[row] = v0;
      hp[NROWS + row] = softplusf(v1) + 0.001f;
      hp[2 * NROWS + row] = v2;
      hp[3 * NROWS + row] = softplusf(v3) + 0.001f;
    }
  }
}

extern "C" void kernel_launch(void* const* d_in, const int* in_sizes, int n_in,
                              void* d_out, int out_size, void* d_ws, size_t ws_size,
                              hipStream_t stream) {
  const float* x  = (const float*)d_in[0];
  const int* sid  = (const int*)d_in[1];
  const float* Wb = (const float*)d_in[2];
  const float* bb = (const float*)d_in[3];
  const float* Wp = (const float*)d_in[4];
  const float* bp = (const float*)d_in[5];
  const float* Ws = (const float*)d_in[6];
  const float* bs = (const float*)d_in[7];
  float* out = (float*)d_out;
  unsigned short* WbT = (unsigned short*)d_ws;            // 768*1024 bf16 = 1.5 MiB
  float* bfoldp = (float*)(WbT + (long)NEXT * DIN);       // 34 f32

  wb_transpose<<<256, 256, 0, stream>>>(Wb, WbT);
  zero_tail<<<444, 256, 0, stream>>>((unsigned*)(WbT + 546 * DIN));
  wfold_rows<<<256, 256, 0, stream>>>(Wb, Wp, Ws, WbT);
  bfold_k<<<1, 64, 0, stream>>>(bb, Wp, bp, Ws, bs, bfoldp);
  gemm_fused<<<1536, 512, 0, stream>>>(x, WbT, bb, sid, bfoldp, out);
}